// Round 5
// baseline (2484.298 us; speedup 1.0000x reference)
//
#include <hip/hip_runtime.h>

// LSTM 2-layer scan: N=1024 rows, T=2048 sequential steps.
// R5 redesign: 512 thr/block (8 waves), 2 lanes per gate-row, K split 28/24
// across the lane pair -> 14 v2f weights/lane (28 VGPR). Working set ~58 fits
// the allocator's preferred 64-VGPR budget (R1-R4: 52-weight set was AGPR-
// parked with per-use v_accvgpr_read, un-hintable). Full occupancy:
// 1024 blocks x 8 waves = 32 waves/CU. Pair-reduce via DPP xor1; gate gather
// via 4 ds_swizzle (8-lane groups, LDS pipe). Layer 2 rotates over 8 waves.

constexpr int H  = 51;
constexpr int TL = 2048;

typedef float v2f __attribute__((ext_vector_type(2)));
typedef float v4f __attribute__((ext_vector_type(4)));

__device__ __forceinline__ float rcpf(float x)   { return __builtin_amdgcn_rcpf(x); }
__device__ __forceinline__ float exp2f_(float x) { return __builtin_amdgcn_exp2f(x); }

constexpr float LOG2E  = 1.442695041f;
constexpr float LOG2E2 = 2.885390082f;

template <int CTRL>
__device__ __forceinline__ float dppmov(float v) {
    return __int_as_float(__builtin_amdgcn_update_dpp(
        0, __float_as_int(v), CTRL, 0xF, 0xF, true));
}

template <int OFF>
__device__ __forceinline__ float swzb(float v) {
    return __int_as_float(__builtin_amdgcn_ds_swizzle(__float_as_int(v), OFF));
}

// full-wave sum, all 64 lanes end with the total (verified R4)
__device__ __forceinline__ float wave_sum(float p) {
    p += dppmov<0xB1>(p);     // quad_perm xor1
    p += dppmov<0x4E>(p);     // quad_perm xor2
    p += dppmov<0x124>(p);    // row_ror:4
    p += dppmov<0x128>(p);    // row_ror:8
    p += swzb<0x401f>(p);     // xor16
    p += __shfl_xor(p, 32, 64);
    return p;
}

__device__ __forceinline__ void pk_fma(v2f& acc, const v2f a, const v2f b) {
    asm("v_pk_fma_f32 %0, %1, %2, %0" : "+v"(acc) : "v"(a), "v"(b));
}

__device__ __forceinline__ void layer2_step(
    const float* __restrict__ hprev, int lane,
    const float4& w2, const float4& wh2, const float4& b2,
    float* __restrict__ c2h2, float* __restrict__ out_ptr)
{
    const float hp = (lane < H) ? hprev[lane] : 0.0f;
    const float p0 = wave_sum(w2.x * hp);
    const float p1 = wave_sum(w2.y * hp);
    const float p2 = wave_sum(w2.z * hp);
    const float p3 = wave_sum(w2.w * hp);
    const float c2 = c2h2[0], h2 = c2h2[1];
    const float a0 = fmaf(wh2.x, h2, p0) + b2.x;
    const float a1 = fmaf(wh2.y, h2, p1) + b2.y;
    const float a2 = fmaf(wh2.z, h2, p2) + b2.z;
    const float a3 = fmaf(wh2.w, h2, p3) + b2.w;
    const float si = rcpf(1.0f + exp2f_(a0 * -LOG2E));
    const float sf = rcpf(1.0f + exp2f_(a1 * -LOG2E));
    const float tg = 1.0f - 2.0f * rcpf(1.0f + exp2f_(a2 * LOG2E2));
    const float so = rcpf(1.0f + exp2f_(a3 * -LOG2E));
    const float c2n = fmaf(sf, c2, si * tg);
    const float h2n = so * (1.0f - 2.0f * rcpf(1.0f + exp2f_(c2n * LOG2E2)));
    if (lane == 0) { c2h2[0] = c2n; c2h2[1] = h2n; *out_ptr = h2n; }
}

__global__ __launch_bounds__(512)
void lstm2_fused(const float* __restrict__ stim,
                 const float* __restrict__ Wih1,
                 const float* __restrict__ Whh1,
                 const float* __restrict__ bih1,
                 const float* __restrict__ bhh1,
                 const float* __restrict__ Wih2,
                 const float* __restrict__ Whh2,
                 const float* __restrict__ bih2,
                 const float* __restrict__ bhh2,
                 float* __restrict__ out)
{
    const int n    = blockIdx.x;
    const int tid  = threadIdx.x;
    const int wid  = tid >> 6;
    const int lane = tid & 63;
    const int half = lane & 1;                    // K-half: 0 -> k[0,28), 1 -> k[28,56)
    const int gate = (lane >> 1) & 3;             // 0=i 1=f 2=g 3=o
    const int unit = wid * 8 + (lane >> 3);       // 0..63, valid < 51
    const bool uval = (unit < H);
    const int kb   = half * 28;

    __shared__ __align__(16) float xrow[TL];
    __shared__ __align__(16) float hbuf[2][56];   // [51..55] stay 0 (pad reads)
    __shared__ float c2h2[2];

    // ---- stage stimulus row, one float4 per thread ----
    {
        const float4* s4 = reinterpret_cast<const float4*>(stim + (size_t)n * TL);
        float4* d4 = reinterpret_cast<float4*>(xrow);
        d4[tid] = s4[tid];
    }

    // ---- layer-1 weights: 14 named v2f pairs (7 v4f-load groups) ----
    const int r = gate * H + unit;
    const float* wr = Whh1 + (size_t)(uval ? r : 0) * H;
    #define SELW(K) (((K) < H && uval) ? wr[((K) < H) ? (K) : 0] : 0.0f)
    v2f wpa0, wpb0, wpa1, wpb1, wpa2, wpb2, wpa3, wpb3, wpa4, wpb4,
        wpa5, wpb5, wpa6, wpb6;
    #define LW(J) wpa##J = (v2f){SELW(kb+4*(J)+0), SELW(kb+4*(J)+1)}; \
                  wpb##J = (v2f){SELW(kb+4*(J)+2), SELW(kb+4*(J)+3)};
    LW(0) LW(1) LW(2) LW(3) LW(4) LW(5) LW(6)
    #undef LW
    #undef SELW
    const float bsum = uval ? (bih1[r] + bhh1[r]) : 0.0f;
    const float wi1  = uval ? Wih1[r] : 0.0f;

    // ---- layer-2 weights ----
    const int lc = (lane < H) ? lane : 0;
    float4 w2c = make_float4(
        (lane < H) ? Wih2[0 * H + lc] : 0.0f,
        (lane < H) ? Wih2[1 * H + lc] : 0.0f,
        (lane < H) ? Wih2[2 * H + lc] : 0.0f,
        (lane < H) ? Wih2[3 * H + lc] : 0.0f);
    float4 wh2c = make_float4(Whh2[0], Whh2[1], Whh2[2], Whh2[3]);
    float4 b2c  = make_float4(bih2[0] + bhh2[0], bih2[1] + bhh2[1],
                              bih2[2] + bhh2[2], bih2[3] + bhh2[3]);

    if (tid < 56) { hbuf[0][tid] = 0.0f; hbuf[1][tid] = 0.0f; }
    if (tid == 0) { c2h2[0] = 0.0f; c2h2[1] = 0.0f; }
    __syncthreads();

    float c1 = 0.0f;
    float* out_row = out + (size_t)n * TL;
    const int rot = (n + (n >> 8)) & 7;   // decorrelate layer-2 wave across co-resident blocks

    for (int t = 0; t < TL; ++t) {
        const float* hprev = hbuf[(t & 1) ^ 1];   // h1(t-1)

        // ---- layer 2 for step t-1 on one rotating wave ----
        if (t > 0 && wid == ((t + rot) & 7)) {
            layer2_step(hprev, lane, w2c, wh2c, b2c, c2h2, out_row + (t - 1));
        }

        // ---- layer 1: this lane's K-half (14 packed FMAs) ----
        const float x = xrow[t];
        const float* hp = hprev + kb;
        v2f acc0 = {0.0f, 0.0f};
        v2f acc1 = {0.0f, 0.0f};
        #define DOT(J) { const v4f hv = *reinterpret_cast<const v4f*>(hp + 4*(J)); \
            const v2f lo = __builtin_shufflevector(hv, hv, 0, 1); \
            const v2f hi = __builtin_shufflevector(hv, hv, 2, 3); \
            pk_fma(acc0, wpa##J, lo); pk_fma(acc1, wpb##J, hi); }
        DOT(0) DOT(1) DOT(2) DOT(3) DOT(4) DOT(5) DOT(6)
        #undef DOT
        float apart = (acc0.x + acc1.x) + (acc0.y + acc1.y);
        apart += dppmov<0xB1>(apart);             // pair-combine (xor1)
        const float a = apart + fmaf(x, wi1, bsum);

        // activation: sigmoid / tanh select via single exp2
        const bool  istanh = (gate == 2);
        const float kk = istanh ? LOG2E2 : -LOG2E;
        const float rr = rcpf(1.0f + exp2f_(a * kk));
        const float v  = istanh ? fmaf(-2.0f, rr, 1.0f) : rr;

        // gather the 8-lane unit-group's 4 gates (BitMode: and=0x18, or=g<<1)
        const float vi = swzb<0x018>(v);
        const float vf = swzb<0x058>(v);
        const float vg = swzb<0x098>(v);
        const float vo = swzb<0x0D8>(v);

        c1 = fmaf(vf, c1, vi * vg);
        const float tr = rcpf(1.0f + exp2f_(c1 * LOG2E2));
        const float h1 = vo * fmaf(-2.0f, tr, 1.0f);
        if (uval && (lane & 7) == 0) hbuf[t & 1][unit] = h1;

        __syncthreads();   // the single per-step barrier
    }

    // ---- drain: layer 2 for t = TL-1 ----
    if (wid == ((TL + rot) & 7)) {
        layer2_step(hbuf[(TL & 1) ^ 1], lane, w2c, wh2c, b2c, c2h2, out_row + (TL - 1));
    }
}

extern "C" void kernel_launch(void* const* d_in, const int* in_sizes, int n_in,
                              void* d_out, int out_size, void* d_ws, size_t ws_size,
                              hipStream_t stream) {
    const float* stim = (const float*)d_in[0];
    const float* Wih1 = (const float*)d_in[1];
    const float* Whh1 = (const float*)d_in[2];
    const float* bih1 = (const float*)d_in[3];
    const float* bhh1 = (const float*)d_in[4];
    const float* Wih2 = (const float*)d_in[5];
    const float* Whh2 = (const float*)d_in[6];
    const float* bih2 = (const float*)d_in[7];
    const float* bhh2 = (const float*)d_in[8];
    float* out = (float*)d_out;

    const int N = in_sizes[0] / TL;   // 1024
    lstm2_fused<<<dim3(N), dim3(512), 0, stream>>>(
        stim, Wih1, Whh1, bih1, bhh1, Wih2, Whh2, bih2, bhh2, out);
}